// Round 5
// baseline (31594.641 us; speedup 1.0000x reference)
//
#include <hip/hip_runtime.h>
#include <hip/hip_fp16.h>

typedef unsigned int u32;
typedef unsigned short u16;
typedef _Float16 h2v __attribute__((ext_vector_type(2)));
typedef short short8 __attribute__((ext_vector_type(8)));
typedef float f32x4 __attribute__((ext_vector_type(4)));

#define MINN 1e-15f

__device__ __forceinline__ float wred(float v){
  #pragma unroll
  for (int m = 32; m > 0; m >>= 1) v += __shfl_xor(v, m, 64);
  return v;
}
__device__ __forceinline__ float bf2f(u32 lo16){ u32 u = lo16 << 16; return __builtin_bit_cast(float, u); }
__device__ __forceinline__ u16 f2bf(float f){
  u32 u = __builtin_bit_cast(u32, f);
  u32 r = (u + 0x7fffu + ((u >> 16) & 1u)) >> 16;
  return (u16)r;
}
__device__ __forceinline__ u16 f16b(float x){ __half h = __float2half(x); return __builtin_bit_cast(u16, h); }
__device__ __forceinline__ u32 pkh(float a, float b){
  u32 lo = f16b(a), hi = f16b(b);
  return lo | (hi << 16);
}
__device__ __forceinline__ float fdot2_(u32 a, u32 b, float c){
  return __builtin_amdgcn_fdot2(__builtin_bit_cast(h2v, a), __builtin_bit_cast(h2v, b), c, false);
}
__device__ __forceinline__ float tanh_fast(float x){
  float e = __expf(-2.f * fabsf(x));
  float t = (1.f - e) / (1.f + e);
  return x < 0.f ? -t : t;
}
__device__ __forceinline__ float artanh_c(float x){
  x = fminf(fmaxf(x, -1.f + 1e-5f), 1.f - 1e-5f);
  return 0.5f * __logf((1.f + x) / (1.f - x));
}
__device__ __forceinline__ float sigm(float x){ return 1.f / (1.f + __expf(-x)); }

// ---------------- weight repack for split scan -----------------------------
// W3[q*32768 + kk*512 + col] (uint4 = 8 fp16 k-values) for column
//   (g=col>>7, i=q*128+(col&127)) : W_all[i][g*512 + 8kk .. +7]
// WD3[q*8192 + kk*128 + j] : W_d[q*128+j][8kk..+7]
__global__ void k_pack2(const float* __restrict__ Wall, const float* __restrict__ Wd,
                        uint4* __restrict__ W3, uint4* __restrict__ WD3, u32* __restrict__ flags){
  int i = blockIdx.x * 256 + threadIdx.x;
  if (i < 131072) {
    int q = i >> 15, rem = i & 32767, kk = rem >> 9, col = rem & 511;
    int g = col >> 7, ii = (q << 7) + (col & 127);
    const float* bsrc = Wall + (size_t)ii * 2048 + (g << 9) + (kk << 3);
    uint4 o;
    o.x = pkh(bsrc[0], bsrc[1]); o.y = pkh(bsrc[2], bsrc[3]);
    o.z = pkh(bsrc[4], bsrc[5]); o.w = pkh(bsrc[6], bsrc[7]);
    W3[i] = o;
  } else if (i < 163840) {
    int e = i - 131072;
    int q = e >> 13, rem = e & 8191, kk = rem >> 7, j = rem & 127;
    int j0 = (q << 7) + j;
    const float* bsrc = Wd + (size_t)j0 * 512 + (kk << 3);
    uint4 o;
    o.x = pkh(bsrc[0], bsrc[1]); o.y = pkh(bsrc[2], bsrc[3]);
    o.z = pkh(bsrc[4], bsrc[5]); o.w = pkh(bsrc[6], bsrc[7]);
    WD3[e] = o;
  } else if (i < 163840 + 3072) {
    flags[i - 163840] = 0u;
  }
}

// ---------------- x -> bf16 + per-row |x|^2 --------------------------------
__global__ void k_convert_x(const float* __restrict__ X, u16* __restrict__ Xb, float* __restrict__ xn2){
  int r = blockIdx.x, t = threadIdx.x;
  const float* row = X + (size_t)r * 512;
  float v0 = row[t], v1 = row[t + 256];
  Xb[(size_t)r * 512 + t] = f2bf(v0);
  Xb[(size_t)r * 512 + t + 256] = f2bf(v1);
  float s = wred(v0 * v0 + v1 * v1);
  __shared__ float p[4];
  if ((t & 63) == 0) p[t >> 6] = s;
  __syncthreads();
  if (t == 0) xn2[r] = p[0] + p[1] + p[2] + p[3];
}

__global__ void k_convert_u(const float* __restrict__ U, u16* __restrict__ Ub){
  int i = blockIdx.x * 256 + threadIdx.x;
  Ub[i] = f2bf(U[i]);
}

// ---------------- mxU = X @ U^T, bf16 MFMA ---------------------------------
__global__ void __launch_bounds__(256) k_gemm(const u16* __restrict__ A, const u16* __restrict__ B,
                                              u16* __restrict__ C){
  __shared__ u16 Al[128 * 32];
  __shared__ u16 Bl[128 * 32];
  int t = threadIdx.x;
  int bn = blockIdx.x, bm = blockIdx.y;
  int w = t >> 6, l = t & 63;
  int wr = w >> 1, wc = w & 1;
  f32x4 zero = {0.f, 0.f, 0.f, 0.f};
  f32x4 acc[4][4];
  #pragma unroll
  for (int m = 0; m < 4; ++m)
    #pragma unroll
    for (int n = 0; n < 4; ++n) acc[m][n] = zero;

  for (int kt = 0; kt < 16; ++kt) {
    #pragma unroll
    for (int i = 0; i < 2; ++i) {
      int off = t + i * 256;
      int r = off >> 2, ch = off & 3;
      *(uint4*)&Al[(size_t)off * 8] = *(const uint4*)(A + (size_t)(bm * 128 + r) * 512 + kt * 32 + ch * 8);
      *(uint4*)&Bl[(size_t)off * 8] = *(const uint4*)(B + (size_t)(bn * 128 + r) * 512 + kt * 32 + ch * 8);
    }
    __syncthreads();
    int ko = (l >> 4) * 8;
    short8 af[4], bfr[4];
    #pragma unroll
    for (int m = 0; m < 4; ++m) af[m] = *(const short8*)&Al[(wr * 64 + m * 16 + (l & 15)) * 32 + ko];
    #pragma unroll
    for (int n = 0; n < 4; ++n) bfr[n] = *(const short8*)&Bl[(wc * 64 + n * 16 + (l & 15)) * 32 + ko];
    #pragma unroll
    for (int m = 0; m < 4; ++m)
      #pragma unroll
      for (int n = 0; n < 4; ++n)
        acc[m][n] = __builtin_amdgcn_mfma_f32_16x16x32_bf16(af[m], bfr[n], acc[m][n], 0, 0, 0);
    __syncthreads();
  }
  int cr = (l >> 4) * 4, cc = l & 15;
  #pragma unroll
  for (int m = 0; m < 4; ++m)
    #pragma unroll
    for (int n = 0; n < 4; ++n)
      #pragma unroll
      for (int r2 = 0; r2 < 4; ++r2) {
        int row = bm * 128 + wr * 64 + m * 16 + cr + r2;
        int col = bn * 128 + wc * 64 + n * 16 + cc;
        C[(size_t)row * 2048 + col] = f2bf(acc[m][n][r2]);
      }
}

// ---------------- per-(row,gate) U-path scalars ----------------------------
__global__ void k_scale(const u16* __restrict__ MXU, const float* __restrict__ xn2,
                        float* __restrict__ SU, float* __restrict__ UY2){
  int r = blockIdx.x, t = threadIdx.x;
  const u16* row = MXU + (size_t)r * 2048;
  uint4 q = *(const uint4*)(row + t * 8);
  float s = 0.f;
  s += bf2f(q.x & 0xffffu) * bf2f(q.x & 0xffffu) + bf2f(q.x >> 16) * bf2f(q.x >> 16);
  s += bf2f(q.y & 0xffffu) * bf2f(q.y & 0xffffu) + bf2f(q.y >> 16) * bf2f(q.y >> 16);
  s += bf2f(q.z & 0xffffu) * bf2f(q.z & 0xffffu) + bf2f(q.z >> 16) * bf2f(q.z >> 16);
  s += bf2f(q.w & 0xffffu) * bf2f(q.w & 0xffffu) + bf2f(q.w >> 16) * bf2f(q.w >> 16);
  s = wred(s);
  if ((t & 63) == 0) {
    int g = t >> 6;
    float mxn = fmaxf(sqrtf(s), MINN);
    float xn = fmaxf(sqrtf(xn2[r]), MINN);
    float tb = tanh_fast((mxn / xn) * artanh_c(xn));
    SU[r * 4 + g] = tb / mxn;
    UY2[r * 4 + g] = tb * tb;
  }
}

// ---------------- split persistent scan ------------------------------------
// 256 blocks x 640 threads. block bid: q = bid>>6 (column slice), b = bid&63.
// threads t<512: gate col (g=t>>7, i=q*128+(t&127)); t>=512: d col j=t-512.
// Per step: 3 flag rounds (F1: h/c/deferred pub, F2: matvec partials, F3: bilinear).
__global__ void __launch_bounds__(640) k_scan2(
    const uint4* __restrict__ W3, const uint4* __restrict__ WD3,
    const u16* __restrict__ MXU, const float* __restrict__ SU, const float* __restrict__ UY2,
    const float* __restrict__ TS, const float* __restrict__ H0, const float* __restrict__ C0,
    u16* __restrict__ Hpub, float* __restrict__ Cpub,
    float* __restrict__ PA, float* __restrict__ PB, float* __restrict__ PD,
    u32* __restrict__ flags,
    float* __restrict__ OutO, float* __restrict__ OutH, float* __restrict__ OutC)
{
  const int bid = blockIdx.x, t = threadIdx.x;
  const int q = bid >> 6, b = bid & 63;
  const int lane = t & 63, wv = t >> 6;
  const bool isG = (t < 512);
  const int g = t >> 7;            // gate (valid when isG)
  const int j = t & 127;           // local index within slice

  u32* F1 = flags + b * 48;
  u32* F2 = F1 + 16;
  u32* F3 = F1 + 32;

  __shared__ __align__(16) u16 Hl[512];
  __shared__ __align__(16) u16 Chl[512];
  __shared__ float Cl[512];
  __shared__ float gl[512];
  __shared__ float ul[128];
  __shared__ float pw[10][2];

  const u32* Hl32 = (const u32*)Hl;
  u16* HpubB = Hpub + b * 512;
  float* CpubB = Cpub + b * 512;

  // ---- init publication (counts as F1 publication #1)
  float hv0 = 0.f, cv0 = 0.f;
  if (!isG) {
    int gi = b * 512 + (q << 7) + (t - 512);
    hv0 = H0[gi]; cv0 = C0[gi];
    HpubB[(q << 7) + (t - 512)] = f16b(hv0);
    CpubB[(q << 7) + (t - 512)] = cv0;
  }
  {
    float sh = wred(hv0 * hv0), sc = wred(cv0 * cv0);
    if (!isG && lane == 0) { pw[wv - 8][0] = sh; pw[wv - 8][1] = sc; }
  }
  __syncthreads();
  if (t == 0) {
    float s0 = pw[0][0] + pw[1][0], s1 = pw[0][1] + pw[1][1];
    float* pd = PD + ((b << 2) + q) * 4;
    pd[0] = s0; pd[1] = s0; pd[2] = s1;
  }
  __threadfence();
  __syncthreads();
  if (t == 0) atomicAdd(F1, 1u);

  const size_t outOb = (size_t)b * (128 * 512);
  float cn2 = 0.f;                 // carried; set at s=0 from PD[2]
  float ov_keep = 0.f, cv_keep = 0.f;

  for (int s = 0; s < 128; ++s) {
    const int row = b * 128 + s;
    const u32 tgt = 4u * (u32)(s + 1);

    // ===== round A: wait for h/c/deferred publication ======================
    if (t == 0) {
      while (__hip_atomic_load(F1, __ATOMIC_RELAXED, __HIP_MEMORY_SCOPE_AGENT) < tgt)
        __builtin_amdgcn_s_sleep(1);
    }
    __syncthreads();
    __threadfence();

    if (isG) {
      Hl[t] = HpubB[t];
      float cc = CpubB[t];
      Cl[t] = cc; Chl[t] = f16b(cc);
    }
    // deferred h-scalars
    float Ssv = 0.f, Sso = 0.f, Sc0 = 0.f;
    #pragma unroll
    for (int qq = 0; qq < 4; ++qq) {
      const float* pd = PD + ((b << 2) + qq) * 4;
      Ssv += pd[0]; Sso += pd[1]; Sc0 += pd[2];
    }
    float HS, hn;
    if (s == 0) {
      HS = 1.f;
      hn = fmaxf(sqrtf(Sso), MINN);
      cn2 = Sc0;
    } else {
      float vn = fmaxf(sqrtf(Ssv), MINN);
      float te = tanh_fast(vn);
      float ke = te / vn;
      float xnh = fmaxf(te, MINN);
      float wxnh = fmaxf(ke * sqrtf(Sso), MINN);
      float th = tanh_fast((wxnh / xnh) * artanh_c(xnh));
      HS = (th / wxnh) * ke;
      hn = fmaxf(th, MINN);
    }
    float cn = fmaxf(sqrtf(cn2), MINN);
    const float tsv = TS[b * 128 + s];
    __syncthreads();               // LDS h/c ready

    // ===== matvec ==========================================================
    float av = 0.f;
    if (isG) {
      const uint4* Wp = W3 + (q << 15) + t;
      #pragma unroll 4
      for (int kk = 0; kk < 64; ++kk) {
        uint4 wq = Wp[kk << 9];
        uint4 hp = *(const uint4*)&Hl32[kk << 2];
        av = fdot2_(wq.x, hp.x, av); av = fdot2_(wq.y, hp.y, av);
        av = fdot2_(wq.z, hp.z, av); av = fdot2_(wq.w, hp.w, av);
      }
      av *= HS;
    } else {
      const uint4* Wp = WD3 + (q << 13) + (t - 512);
      const u32* Cl32 = (const u32*)Chl;
      #pragma unroll 4
      for (int kk = 0; kk < 64; ++kk) {
        uint4 wq = Wp[kk << 7];
        uint4 cp = *(const uint4*)&Cl32[kk << 2];
        av = fdot2_(wq.x, cp.x, av); av = fdot2_(wq.y, cp.y, av);
        av = fdot2_(wq.z, cp.z, av); av = fdot2_(wq.w, cp.w, av);
      }
    }
    float ux = 0.f;
    if (isG) ux = bf2f((u32)MXU[(size_t)row * 2048 + (g << 9) + (q << 7) + j]);

    {
      float s0 = wred(av * av);
      float s1 = wred(isG ? av * ux : 0.f);
      if (lane == 0) { pw[wv][0] = s0; pw[wv][1] = s1; }
    }
    __syncthreads();
    if (t < 9) {
      float val;
      if (t < 8) { int gg = t >> 1, e = t & 1; val = pw[2 * gg][e] + pw[2 * gg + 1][e]; }
      else       { val = pw[8][0] + pw[9][0]; }
      PA[((b << 2) + q) * 16 + t] = val;
    }
    __threadfence();
    __syncthreads();
    if (t == 0) atomicAdd(F2, 1u);
    if (t == 0) {
      while (__hip_atomic_load(F2, __ATOMIC_RELAXED, __HIP_MEMORY_SCOPE_AGENT) < tgt)
        __builtin_amdgcn_s_sleep(1);
    }
    __syncthreads();
    __threadfence();

    // ===== round A scalars + elementwise gates / u =========================
    float uval = 0.f;
    if (isG) {
      float gsq = 0.f, gdt = 0.f;
      #pragma unroll
      for (int qq = 0; qq < 4; ++qq) {
        const float* pa = PA + ((b << 2) + qq) * 16;
        gsq += pa[2 * g]; gdt += pa[2 * g + 1];
      }
      float su_ = SU[row * 4 + g], y2 = UY2[row * 4 + g];
      float mxn = fmaxf(sqrtf(gsq), MINN);
      float tw = tanh_fast((mxn / hn) * artanh_c(hn));
      float x2 = tw * tw;
      float sw = tw / mxn;
      float xy = sw * su_ * gdt;
      float na = 1.f + 2.f * xy + y2, nb = 1.f - x2;
      float den = fmaxf(1.f + 2.f * xy + x2 * y2, MINN);
      float addn2 = fmaxf((na * na * x2 + 2.f * na * nb * xy + nb * nb * y2) / (den * den), 0.f);
      float an = fmaxf(sqrtf(addn2), MINN);
      float lam = artanh_c(an) / an;
      float GA = lam * na * sw / den, GB = lam * nb * su_ / den;
      float gval = sigm(GA * av + GB * ux);
      gl[t] = gval;
      if (g == 2) OutO[outOb + (size_t)s * 512 + (q << 7) + j] = gval;
    } else {
      float md2 = 0.f;
      #pragma unroll
      for (int qq = 0; qq < 4; ++qq) md2 += PA[((b << 2) + qq) * 16 + 8];
      float mdn = fmaxf(sqrtf(md2), MINN);
      float alc = tanh_fast((mdn / cn) * artanh_c(cn));
      float ycl = fmaxf(alc, MINN);
      float DS = (artanh_c(ycl) / ycl) * alc / mdn;
      uval = tanh_fast(DS * av);
      ul[t - 512] = uval;
    }
    __syncthreads();

    // ===== bilinear partial sums (9 sums over local j in [0,128)) ==========
    if (wv < 9) {
      float acc2 = 0.f;
      #pragma unroll
      for (int rep = 0; rep < 2; ++rep) {
        int jj = lane + rep * 64;
        float fj = gl[jj], ij = gl[128 + jj], cgj = gl[384 + jj];
        float uj = ul[jj], cj = Cl[(q << 7) + jj];
        float wx1 = ij * cgj;
        float p;
        if      (wv == 0) p = uj * uj;
        else if (wv == 1) p = uj * cj;
        else if (wv == 2) p = cgj * cgj;
        else if (wv == 3) p = wx1 * wx1;
        else if (wv == 4) p = fj * fj * uj * uj;
        else if (wv == 5) p = fj * fj * uj * cj;
        else if (wv == 6) p = fj * fj * cj * cj;
        else if (wv == 7) p = wx1 * fj * uj;
        else              p = wx1 * fj * cj;
        acc2 += p;
      }
      acc2 = wred(acc2);
      if (lane == 0) PB[((b << 2) + q) * 16 + wv] = acc2;
    }
    __threadfence();
    __syncthreads();
    if (t == 0) atomicAdd(F3, 1u);
    if (t == 0) {
      while (__hip_atomic_load(F3, __ATOMIC_RELAXED, __HIP_MEMORY_SCOPE_AGENT) < tgt)
        __builtin_amdgcn_s_sleep(1);
    }
    __syncthreads();
    __threadfence();

    // ===== combine bilinear sums, scalar chain (all threads, redundant) ====
    float S0 = 0.f, S1 = 0.f, S2 = 0.f, S3 = 0.f, S4 = 0.f, S5 = 0.f, S6 = 0.f, S7 = 0.f, S8 = 0.f;
    #pragma unroll
    for (int qq = 0; qq < 4; ++qq) {
      const float* pb = PB + ((b << 2) + qq) * 16;
      S0 += pb[0]; S1 += pb[1]; S2 += pb[2]; S3 += pb[3]; S4 += pb[4];
      S5 += pb[5]; S6 += pb[6]; S7 += pb[7]; S8 += pb[8];
    }
    float usq = S0, duc = S1;
    float un = fmaxf(sqrtf(usq), MINN);
    float t1 = tanh_fast(un);
    float at1 = artanh_c(t1);
    float k1 = t1 / un;
    float k2 = tanh_fast(tsv * at1) / un;
    float x2l = t1 * t1;
    float xyl = -k1 * duc;
    float nal = 1.f + 2.f * xyl + cn2;
    float nbl = 1.f - x2l;
    float denl = fmaxf(1.f + 2.f * xyl + x2l * cn2, MINN);
    float p1 = -nal * k1 / denl, p2 = nbl / denl;
    float cl2 = fmaxf(p1 * p1 * usq + 2.f * p1 * p2 * duc + p2 * p2 * cn2, 0.f);
    float cs2n2 = k2 * k2 * usq;
    float xya = k2 * (p1 * usq + p2 * duc);
    float naa = 1.f + 2.f * xya + cs2n2;
    float nba = 1.f - cl2;
    float dena = fmaxf(1.f + 2.f * xya + cl2 * cs2n2, MINN);
    float r1 = (naa * p1 + nba * k2) / dena;
    float r2 = naa * p2 / dena;
    float cadj2 = fmaxf(r1 * r1 * usq + 2.f * r1 * r2 * duc + r2 * r2 * cn2, 0.f);

    float xnp = fmaxf(sqrtf(S2), MINN);
    float wxnp = fmaxf(sqrtf(S3), MINN);
    float tp = tanh_fast((wxnp / xnp) * artanh_c(xnp));
    float s1c = tp / wxnp;
    float Ssw2 = r1 * r1 * S4 + 2.f * r1 * r2 * S5 + r2 * r2 * S6;
    float xnq = fmaxf(sqrtf(cadj2), MINN);
    float wxnq = fmaxf(sqrtf(Ssw2), MINN);
    float tq = tanh_fast((wxnq / xnq) * artanh_c(xnq));
    float s2c = tq / wxnq;
    float Ss12 = r1 * S7 + r2 * S8;
    float xyn = s1c * s2c * Ss12;
    float na2 = 1.f + 2.f * xyn + tq * tq;
    float nb2 = 1.f - tp * tp;
    float den2 = fmaxf(1.f + 2.f * xyn + tp * tp * tq * tq, MINN);
    float CA = na2 * s1c / den2, CB = nb2 * s2c / den2;
    cn2 = fmaxf((na2 * na2 * tp * tp + 2.f * na2 * nb2 * xyn + nb2 * nb2 * tq * tq) / (den2 * den2), 0.f);

    // ===== elementwise c_new / v / ov + publish ============================
    float vv = 0.f, ovv = 0.f;
    if (!isG) {
      int jj = t - 512;
      float cj = Cl[(q << 7) + jj];
      float wx1 = gl[128 + jj] * gl[384 + jj];
      float cadj = r1 * uval + r2 * cj;
      float cnew = CA * wx1 + CB * gl[jj] * cadj;
      vv = tanh_fast(cnew);
      ovv = gl[256 + jj] * vv;
      cv_keep = cnew; ov_keep = ovv;
      HpubB[(q << 7) + jj] = f16b(ovv);
      CpubB[(q << 7) + jj] = cnew;
    }
    {
      float sv = wred(vv * vv), so = wred(ovv * ovv);
      if (!isG && lane == 0) { pw[wv - 8][0] = sv; pw[wv - 8][1] = so; }
    }
    __syncthreads();
    if (t == 0) {
      float* pd = PD + ((b << 2) + q) * 4;
      pd[0] = pw[0][0] + pw[1][0];
      pd[1] = pw[0][1] + pw[1][1];
    }
    __threadfence();
    __syncthreads();
    if (t == 0) atomicAdd(F1, 1u);
  }

  // ===== final: resolve deferred HS for h_final ============================
  if (t == 0) {
    while (__hip_atomic_load(F1, __ATOMIC_RELAXED, __HIP_MEMORY_SCOPE_AGENT) < 4u * 129u)
      __builtin_amdgcn_s_sleep(1);
  }
  __syncthreads();
  __threadfence();
  {
    float Ssv = 0.f, Sso = 0.f;
    #pragma unroll
    for (int qq = 0; qq < 4; ++qq) {
      const float* pd = PD + ((b << 2) + qq) * 4;
      Ssv += pd[0]; Sso += pd[1];
    }
    float vn = fmaxf(sqrtf(Ssv), MINN);
    float te = tanh_fast(vn);
    float ke = te / vn;
    float xnh = fmaxf(te, MINN);
    float wxnh = fmaxf(ke * sqrtf(Sso), MINN);
    float th = tanh_fast((wxnh / xnh) * artanh_c(xnh));
    float HSf = (th / wxnh) * ke;
    if (!isG) {
      int jj = t - 512;
      OutH[b * 512 + (q << 7) + jj] = HSf * ov_keep;
      OutC[b * 512 + (q << 7) + jj] = cv_keep;
    }
  }
}

extern "C" void kernel_launch(void* const* d_in, const int* in_sizes, int n_in,
                              void* d_out, int out_size, void* d_ws, size_t ws_size,
                              hipStream_t stream) {
  const float* inputs = (const float*)d_in[0];   // [64,128,512]
  const float* tsg    = (const float*)d_in[1];   // [64,128]
  const float* h0g    = (const float*)d_in[2];   // [64,512]
  const float* c0g    = (const float*)d_in[3];   // [64,512]
  const float* Wall   = (const float*)d_in[4];   // [512,2048]
  const float* Uall   = (const float*)d_in[5];   // [2048,512]
  const float* Wd     = (const float*)d_in[6];   // [512,512]
  char* ws = (char*)d_ws;

  uint4* W3   = (uint4*)(ws + 0);                // 2 MB
  uint4* WD3  = (uint4*)(ws + 2097152);          // 512 KB
  u16*   XB   = (u16*)(ws + 2621440);            // 8 MB
  u16*   UB   = (u16*)(ws + 11010048);           // 2 MB
  u16*   MXU  = (u16*)(ws + 13107200);           // 32 MB
  float* XN2  = (float*)(ws + 46661632);         // 32 KB
  float* SU   = (float*)(ws + 46694400);         // 128 KB
  float* UY2  = (float*)(ws + 46825472);         // 128 KB
  u16*   Hpub = (u16*)(ws + 46956544);           // 64 KB
  float* Cpub = (float*)(ws + 47022080);         // 128 KB
  float* PA   = (float*)(ws + 47153152);         // 16 KB
  float* PB   = (float*)(ws + 47169536);         // 16 KB
  float* PD   = (float*)(ws + 47185920);         // 4 KB
  u32*   FLG  = (u32*)(ws + 47190016);           // 12 KB

  float* out = (float*)d_out;
  float* out_o = out;                            // [64,128,512]
  float* out_h = out + 4194304;                  // [64,512]
  float* out_c = out + 4227072;                  // [64,512]

  k_pack2<<<653, 256, 0, stream>>>(Wall, Wd, W3, WD3, FLG);
  k_convert_x<<<8192, 256, 0, stream>>>(inputs, XB, XN2);
  k_convert_u<<<4096, 256, 0, stream>>>(Uall, UB);
  k_gemm<<<dim3(16, 64), 256, 0, stream>>>(XB, UB, MXU);
  k_scale<<<8192, 256, 0, stream>>>(MXU, XN2, SU, UY2);
  k_scan2<<<256, 640, 0, stream>>>(W3, WD3, MXU, SU, UY2, tsg, h0g, c0g,
                                   Hpub, Cpub, PA, PB, PD, FLG,
                                   out_o, out_h, out_c);
}

// Round 7
// 31507.321 us; speedup vs baseline: 1.0028x; 1.0028x over previous
//
#include <hip/hip_runtime.h>
#include <hip/hip_fp16.h>

typedef unsigned int u32;
typedef unsigned short u16;
typedef _Float16 h2v __attribute__((ext_vector_type(2)));
typedef short short8 __attribute__((ext_vector_type(8)));
typedef float f32x4 __attribute__((ext_vector_type(4)));

#define MINN 1e-15f

// RMW-poll: executes at the memory-side coherence point -> always fresh.
// (Plain atomic LOADs can spin on a stale XCD-L2 line: peer atomicAdd does
// NOT back-invalidate remote L2; R5 measured ~80us/round from eviction-paced
// staleness.)
__device__ __forceinline__ u32 poll_flag(u32* f){
  return __hip_atomic_fetch_add(f, 0u, __ATOMIC_RELAXED, __HIP_MEMORY_SCOPE_AGENT);
}

__device__ __forceinline__ float wred(float v){
  #pragma unroll
  for (int m = 32; m > 0; m >>= 1) v += __shfl_xor(v, m, 64);
  return v;
}
__device__ __forceinline__ float bf2f(u32 lo16){ u32 u = lo16 << 16; return __builtin_bit_cast(float, u); }
__device__ __forceinline__ u16 f2bf(float f){
  u32 u = __builtin_bit_cast(u32, f);
  u32 r = (u + 0x7fffu + ((u >> 16) & 1u)) >> 16;
  return (u16)r;
}
__device__ __forceinline__ u16 f16b(float x){ __half h = __float2half(x); return __builtin_bit_cast(u16, h); }
__device__ __forceinline__ u32 pkh(float a, float b){
  u32 lo = f16b(a), hi = f16b(b);
  return lo | (hi << 16);
}
__device__ __forceinline__ float fdot2_(u32 a, u32 b, float c){
  return __builtin_amdgcn_fdot2(__builtin_bit_cast(h2v, a), __builtin_bit_cast(h2v, b), c, false);
}
__device__ __forceinline__ float tanh_fast(float x){
  float e = __expf(-2.f * fabsf(x));
  float t = (1.f - e) / (1.f + e);
  return x < 0.f ? -t : t;
}
__device__ __forceinline__ float artanh_c(float x){
  x = fminf(fmaxf(x, -1.f + 1e-5f), 1.f - 1e-5f);
  return 0.5f * __logf((1.f + x) / (1.f - x));
}
__device__ __forceinline__ float sigm(float x){ return 1.f / (1.f + __expf(-x)); }

// ---------------- weight repack for split scan -----------------------------
__global__ void k_pack2(const float* __restrict__ Wall, const float* __restrict__ Wd,
                        uint4* __restrict__ W3, uint4* __restrict__ WD3, u32* __restrict__ flags){
  int i = blockIdx.x * 256 + threadIdx.x;
  if (i < 131072) {
    int q = i >> 15, rem = i & 32767, kk = rem >> 9, col = rem & 511;
    int g = col >> 7, ii = (q << 7) + (col & 127);
    const float* bsrc = Wall + (size_t)ii * 2048 + (g << 9) + (kk << 3);
    uint4 o;
    o.x = pkh(bsrc[0], bsrc[1]); o.y = pkh(bsrc[2], bsrc[3]);
    o.z = pkh(bsrc[4], bsrc[5]); o.w = pkh(bsrc[6], bsrc[7]);
    W3[i] = o;
  } else if (i < 163840) {
    int e = i - 131072;
    int q = e >> 13, rem = e & 8191, kk = rem >> 7, j = rem & 127;
    int j0 = (q << 7) + j;
    const float* bsrc = Wd + (size_t)j0 * 512 + (kk << 3);
    uint4 o;
    o.x = pkh(bsrc[0], bsrc[1]); o.y = pkh(bsrc[2], bsrc[3]);
    o.z = pkh(bsrc[4], bsrc[5]); o.w = pkh(bsrc[6], bsrc[7]);
    WD3[e] = o;
  } else if (i < 163840 + 3072) {
    flags[i - 163840] = 0u;
  }
}

// ---------------- x -> bf16 + per-row |x|^2 --------------------------------
__global__ void k_convert_x(const float* __restrict__ X, u16* __restrict__ Xb, float* __restrict__ xn2){
  int r = blockIdx.x, t = threadIdx.x;
  const float* row = X + (size_t)r * 512;
  float v0 = row[t], v1 = row[t + 256];
  Xb[(size_t)r * 512 + t] = f2bf(v0);
  Xb[(size_t)r * 512 + t + 256] = f2bf(v1);
  float s = wred(v0 * v0 + v1 * v1);
  __shared__ float p[4];
  if ((t & 63) == 0) p[t >> 6] = s;
  __syncthreads();
  if (t == 0) xn2[r] = p[0] + p[1] + p[2] + p[3];
}

__global__ void k_convert_u(const float* __restrict__ U, u16* __restrict__ Ub){
  int i = blockIdx.x * 256 + threadIdx.x;
  Ub[i] = f2bf(U[i]);
}

// ---------------- mxU = X @ U^T, bf16 MFMA ---------------------------------
__global__ void __launch_bounds__(256) k_gemm(const u16* __restrict__ A, const u16* __restrict__ B,
                                              u16* __restrict__ C){
  __shared__ u16 Al[128 * 32];
  __shared__ u16 Bl[128 * 32];
  int t = threadIdx.x;
  int bn = blockIdx.x, bm = blockIdx.y;
  int w = t >> 6, l = t & 63;
  int wr = w >> 1, wc = w & 1;
  f32x4 zero = {0.f, 0.f, 0.f, 0.f};
  f32x4 acc[4][4];
  #pragma unroll
  for (int m = 0; m < 4; ++m)
    #pragma unroll
    for (int n = 0; n < 4; ++n) acc[m][n] = zero;

  for (int kt = 0; kt < 16; ++kt) {
    #pragma unroll
    for (int i = 0; i < 2; ++i) {
      int off = t + i * 256;
      int r = off >> 2, ch = off & 3;
      *(uint4*)&Al[(size_t)off * 8] = *(const uint4*)(A + (size_t)(bm * 128 + r) * 512 + kt * 32 + ch * 8);
      *(uint4*)&Bl[(size_t)off * 8] = *(const uint4*)(B + (size_t)(bn * 128 + r) * 512 + kt * 32 + ch * 8);
    }
    __syncthreads();
    int ko = (l >> 4) * 8;
    short8 af[4], bfr[4];
    #pragma unroll
    for (int m = 0; m < 4; ++m) af[m] = *(const short8*)&Al[(wr * 64 + m * 16 + (l & 15)) * 32 + ko];
    #pragma unroll
    for (int n = 0; n < 4; ++n) bfr[n] = *(const short8*)&Bl[(wc * 64 + n * 16 + (l & 15)) * 32 + ko];
    #pragma unroll
    for (int m = 0; m < 4; ++m)
      #pragma unroll
      for (int n = 0; n < 4; ++n)
        acc[m][n] = __builtin_amdgcn_mfma_f32_16x16x32_bf16(af[m], bfr[n], acc[m][n], 0, 0, 0);
    __syncthreads();
  }
  int cr = (l >> 4) * 4, cc = l & 15;
  #pragma unroll
  for (int m = 0; m < 4; ++m)
    #pragma unroll
    for (int n = 0; n < 4; ++n)
      #pragma unroll
      for (int r2 = 0; r2 < 4; ++r2) {
        int row = bm * 128 + wr * 64 + m * 16 + cr + r2;
        int col = bn * 128 + wc * 64 + n * 16 + cc;
        C[(size_t)row * 2048 + col] = f2bf(acc[m][n][r2]);
      }
}

// ---------------- per-(row,gate) U-path scalars ----------------------------
__global__ void k_scale(const u16* __restrict__ MXU, const float* __restrict__ xn2,
                        float* __restrict__ SU, float* __restrict__ UY2){
  int r = blockIdx.x, t = threadIdx.x;
  const u16* row = MXU + (size_t)r * 2048;
  uint4 q = *(const uint4*)(row + t * 8);
  float s = 0.f;
  s += bf2f(q.x & 0xffffu) * bf2f(q.x & 0xffffu) + bf2f(q.x >> 16) * bf2f(q.x >> 16);
  s += bf2f(q.y & 0xffffu) * bf2f(q.y & 0xffffu) + bf2f(q.y >> 16) * bf2f(q.y >> 16);
  s += bf2f(q.z & 0xffffu) * bf2f(q.z & 0xffffu) + bf2f(q.z >> 16) * bf2f(q.z >> 16);
  s += bf2f(q.w & 0xffffu) * bf2f(q.w & 0xffffu) + bf2f(q.w >> 16) * bf2f(q.w >> 16);
  s = wred(s);
  if ((t & 63) == 0) {
    int g = t >> 6;
    float mxn = fmaxf(sqrtf(s), MINN);
    float xn = fmaxf(sqrtf(xn2[r]), MINN);
    float tb = tanh_fast((mxn / xn) * artanh_c(xn));
    SU[r * 4 + g] = tb / mxn;
    UY2[r * 4 + g] = tb * tb;
  }
}

// ---------------- split persistent scan ------------------------------------
// 256 blocks x 640 threads. block bid: q = bid>>6 (column slice), b = bid&63.
// NOTE: blocks of a batch differ by 64 in bid (64%8==0) -> co-XCD under the
// round-robin XCD mapping; data (Hpub/Cpub/partials) stays coherent via the
// shared XCD L2 + reader-side __threadfence (L1 inv). Flags use RMW-poll.
__global__ void __launch_bounds__(640) k_scan2(
    const uint4* __restrict__ W3, const uint4* __restrict__ WD3,
    const u16* __restrict__ MXU, const float* __restrict__ SU, const float* __restrict__ UY2,
    const float* __restrict__ TS, const float* __restrict__ H0, const float* __restrict__ C0,
    u16* __restrict__ Hpub, float* __restrict__ Cpub,
    float* __restrict__ PA, float* __restrict__ PB, float* __restrict__ PD,
    u32* __restrict__ flags,
    float* __restrict__ OutO, float* __restrict__ OutH, float* __restrict__ OutC)
{
  const int bid = blockIdx.x, t = threadIdx.x;
  const int q = bid >> 6, b = bid & 63;
  const int lane = t & 63, wv = t >> 6;
  const bool isG = (t < 512);
  const int g = t >> 7;            // gate (valid when isG)
  const int j = t & 127;           // local index within slice

  u32* F1 = flags + b * 48;
  u32* F2 = F1 + 16;
  u32* F3 = F1 + 32;

  __shared__ __align__(16) u16 Hl[512];
  __shared__ __align__(16) u16 Chl[512];
  __shared__ float Cl[512];
  __shared__ float gl[512];
  __shared__ float ul[128];
  __shared__ float pw[10][2];

  const u32* Hl32 = (const u32*)Hl;
  u16* HpubB = Hpub + b * 512;
  float* CpubB = Cpub + b * 512;

  // ---- init publication (counts as F1 publication #1)
  float hv0 = 0.f, cv0 = 0.f;
  if (!isG) {
    int gi = b * 512 + (q << 7) + (t - 512);
    hv0 = H0[gi]; cv0 = C0[gi];
    HpubB[(q << 7) + (t - 512)] = f16b(hv0);
    CpubB[(q << 7) + (t - 512)] = cv0;
  }
  {
    float sh = wred(hv0 * hv0), sc = wred(cv0 * cv0);
    if (!isG && lane == 0) { pw[wv - 8][0] = sh; pw[wv - 8][1] = sc; }
  }
  __syncthreads();
  if (t == 0) {
    float s0 = pw[0][0] + pw[1][0], s1 = pw[0][1] + pw[1][1];
    float* pd = PD + ((b << 2) + q) * 4;
    pd[0] = s0; pd[1] = s0; pd[2] = s1;
  }
  __threadfence();
  __syncthreads();
  if (t == 0) atomicAdd(F1, 1u);

  const size_t outOb = (size_t)b * (128 * 512);
  float cn2 = 0.f;                 // carried; set at s=0 from PD[2]
  float ov_keep = 0.f, cv_keep = 0.f;

  for (int s = 0; s < 128; ++s) {
    const int row = b * 128 + s;
    const u32 tgt = 4u * (u32)(s + 1);

    // ===== round A: wait for h/c/deferred publication ======================
    if (t == 0) {
      while (poll_flag(F1) < tgt)
        __builtin_amdgcn_s_sleep(1);
    }
    __syncthreads();
    __threadfence();

    if (isG) {
      Hl[t] = HpubB[t];
      float cc = CpubB[t];
      Cl[t] = cc; Chl[t] = f16b(cc);
    }
    // deferred h-scalars
    float Ssv = 0.f, Sso = 0.f, Sc0 = 0.f;
    #pragma unroll
    for (int qq = 0; qq < 4; ++qq) {
      const float* pd = PD + ((b << 2) + qq) * 4;
      Ssv += pd[0]; Sso += pd[1]; Sc0 += pd[2];
    }
    float HS, hn;
    if (s == 0) {
      HS = 1.f;
      hn = fmaxf(sqrtf(Sso), MINN);
      cn2 = Sc0;
    } else {
      float vn = fmaxf(sqrtf(Ssv), MINN);
      float te = tanh_fast(vn);
      float ke = te / vn;
      float xnh = fmaxf(te, MINN);
      float wxnh = fmaxf(ke * sqrtf(Sso), MINN);
      float th = tanh_fast((wxnh / xnh) * artanh_c(xnh));
      HS = (th / wxnh) * ke;
      hn = fmaxf(th, MINN);
    }
    float cn = fmaxf(sqrtf(cn2), MINN);
    const float tsv = TS[b * 128 + s];
    __syncthreads();               // LDS h/c ready

    // ===== matvec ==========================================================
    float av = 0.f;
    if (isG) {
      const uint4* Wp = W3 + (q << 15) + t;
      #pragma unroll 4
      for (int kk = 0; kk < 64; ++kk) {
        uint4 wq = Wp[kk << 9];
        uint4 hp = *(const uint4*)&Hl32[kk << 2];
        av = fdot2_(wq.x, hp.x, av); av = fdot2_(wq.y, hp.y, av);
        av = fdot2_(wq.z, hp.z, av); av = fdot2_(wq.w, hp.w, av);
      }
      av *= HS;
    } else {
      const uint4* Wp = WD3 + (q << 13) + (t - 512);
      const u32* Cl32 = (const u32*)Chl;
      #pragma unroll 4
      for (int kk = 0; kk < 64; ++kk) {
        uint4 wq = Wp[kk << 7];
        uint4 cp = *(const uint4*)&Cl32[kk << 2];
        av = fdot2_(wq.x, cp.x, av); av = fdot2_(wq.y, cp.y, av);
        av = fdot2_(wq.z, cp.z, av); av = fdot2_(wq.w, cp.w, av);
      }
    }
    float ux = 0.f;
    if (isG) ux = bf2f((u32)MXU[(size_t)row * 2048 + (g << 9) + (q << 7) + j]);

    {
      float s0 = wred(av * av);
      float s1 = wred(isG ? av * ux : 0.f);
      if (lane == 0) { pw[wv][0] = s0; pw[wv][1] = s1; }
    }
    __syncthreads();
    if (t < 9) {
      float val;
      if (t < 8) { int gg = t >> 1, e = t & 1; val = pw[2 * gg][e] + pw[2 * gg + 1][e]; }
      else       { val = pw[8][0] + pw[9][0]; }
      PA[((b << 2) + q) * 16 + t] = val;
    }
    __threadfence();
    __syncthreads();
    if (t == 0) atomicAdd(F2, 1u);
    if (t == 0) {
      while (poll_flag(F2) < tgt)
        __builtin_amdgcn_s_sleep(1);
    }
    __syncthreads();
    __threadfence();

    // ===== round A scalars + elementwise gates / u =========================
    float uval = 0.f;
    if (isG) {
      float gsq = 0.f, gdt = 0.f;
      #pragma unroll
      for (int qq = 0; qq < 4; ++qq) {
        const float* pa = PA + ((b << 2) + qq) * 16;
        gsq += pa[2 * g]; gdt += pa[2 * g + 1];
      }
      float su_ = SU[row * 4 + g], y2 = UY2[row * 4 + g];
      float mxn = fmaxf(sqrtf(gsq), MINN);
      float tw = tanh_fast((mxn / hn) * artanh_c(hn));
      float x2 = tw * tw;
      float sw = tw / mxn;
      float xy = sw * su_ * gdt;
      float na = 1.f + 2.f * xy + y2, nb = 1.f - x2;
      float den = fmaxf(1.f + 2.f * xy + x2 * y2, MINN);
      float addn2 = fmaxf((na * na * x2 + 2.f * na * nb * xy + nb * nb * y2) / (den * den), 0.f);
      float an = fmaxf(sqrtf(addn2), MINN);
      float lam = artanh_c(an) / an;
      float GA = lam * na * sw / den, GB = lam * nb * su_ / den;
      float gval = sigm(GA * av + GB * ux);
      gl[t] = gval;
      if (g == 2) OutO[outOb + (size_t)s * 512 + (q << 7) + j] = gval;
    } else {
      float md2 = 0.f;
      #pragma unroll
      for (int qq = 0; qq < 4; ++qq) md2 += PA[((b << 2) + qq) * 16 + 8];
      float mdn = fmaxf(sqrtf(md2), MINN);
      float alc = tanh_fast((mdn / cn) * artanh_c(cn));
      float ycl = fmaxf(alc, MINN);
      float DS = (artanh_c(ycl) / ycl) * alc / mdn;
      uval = tanh_fast(DS * av);
      ul[t - 512] = uval;
    }
    __syncthreads();

    // ===== bilinear partial sums (9 sums over local j in [0,128)) ==========
    if (wv < 9) {
      float acc2 = 0.f;
      #pragma unroll
      for (int rep = 0; rep < 2; ++rep) {
        int jj = lane + rep * 64;
        float fj = gl[jj], ij = gl[128 + jj], cgj = gl[384 + jj];
        float uj = ul[jj], cj = Cl[(q << 7) + jj];
        float wx1 = ij * cgj;
        float p;
        if      (wv == 0) p = uj * uj;
        else if (wv == 1) p = uj * cj;
        else if (wv == 2) p = cgj * cgj;
        else if (wv == 3) p = wx1 * wx1;
        else if (wv == 4) p = fj * fj * uj * uj;
        else if (wv == 5) p = fj * fj * uj * cj;
        else if (wv == 6) p = fj * fj * cj * cj;
        else if (wv == 7) p = wx1 * fj * uj;
        else              p = wx1 * fj * cj;
        acc2 += p;
      }
      acc2 = wred(acc2);
      if (lane == 0) PB[((b << 2) + q) * 16 + wv] = acc2;
    }
    __threadfence();
    __syncthreads();
    if (t == 0) atomicAdd(F3, 1u);
    if (t == 0) {
      while (poll_flag(F3) < tgt)
        __builtin_amdgcn_s_sleep(1);
    }
    __syncthreads();
    __threadfence();

    // ===== combine bilinear sums, scalar chain (all threads, redundant) ====
    float S0 = 0.f, S1 = 0.f, S2 = 0.f, S3 = 0.f, S4 = 0.f, S5 = 0.f, S6 = 0.f, S7 = 0.f, S8 = 0.f;
    #pragma unroll
    for (int qq = 0; qq < 4; ++qq) {
      const float* pb = PB + ((b << 2) + qq) * 16;
      S0 += pb[0]; S1 += pb[1]; S2 += pb[2]; S3 += pb[3]; S4 += pb[4];
      S5 += pb[5]; S6 += pb[6]; S7 += pb[7]; S8 += pb[8];
    }
    float usq = S0, duc = S1;
    float un = fmaxf(sqrtf(usq), MINN);
    float t1 = tanh_fast(un);
    float at1 = artanh_c(t1);
    float k1 = t1 / un;
    float k2 = tanh_fast(tsv * at1) / un;
    float x2l = t1 * t1;
    float xyl = -k1 * duc;
    float nal = 1.f + 2.f * xyl + cn2;
    float nbl = 1.f - x2l;
    float denl = fmaxf(1.f + 2.f * xyl + x2l * cn2, MINN);
    float p1 = -nal * k1 / denl, p2 = nbl / denl;
    float cl2 = fmaxf(p1 * p1 * usq + 2.f * p1 * p2 * duc + p2 * p2 * cn2, 0.f);
    float cs2n2 = k2 * k2 * usq;
    float xya = k2 * (p1 * usq + p2 * duc);
    float naa = 1.f + 2.f * xya + cs2n2;
    float nba = 1.f - cl2;
    float dena = fmaxf(1.f + 2.f * xya + cl2 * cs2n2, MINN);
    float r1 = (naa * p1 + nba * k2) / dena;
    float r2 = naa * p2 / dena;
    float cadj2 = fmaxf(r1 * r1 * usq + 2.f * r1 * r2 * duc + r2 * r2 * cn2, 0.f);

    float xnp = fmaxf(sqrtf(S2), MINN);
    float wxnp = fmaxf(sqrtf(S3), MINN);
    float tp = tanh_fast((wxnp / xnp) * artanh_c(xnp));
    float s1c = tp / wxnp;
    float Ssw2 = r1 * r1 * S4 + 2.f * r1 * r2 * S5 + r2 * r2 * S6;
    float xnq = fmaxf(sqrtf(cadj2), MINN);
    float wxnq = fmaxf(sqrtf(Ssw2), MINN);
    float tq = tanh_fast((wxnq / xnq) * artanh_c(xnq));
    float s2c = tq / wxnq;
    float Ss12 = r1 * S7 + r2 * S8;
    float xyn = s1c * s2c * Ss12;
    float na2 = 1.f + 2.f * xyn + tq * tq;
    float nb2 = 1.f - tp * tp;
    float den2 = fmaxf(1.f + 2.f * xyn + tp * tp * tq * tq, MINN);
    float CA = na2 * s1c / den2, CB = nb2 * s2c / den2;
    cn2 = fmaxf((na2 * na2 * tp * tp + 2.f * na2 * nb2 * xyn + nb2 * nb2 * tq * tq) / (den2 * den2), 0.f);

    // ===== elementwise c_new / v / ov + publish ============================
    float vv = 0.f, ovv = 0.f;
    if (!isG) {
      int jj = t - 512;
      float cj = Cl[(q << 7) + jj];
      float wx1 = gl[128 + jj] * gl[384 + jj];
      float cadj = r1 * uval + r2 * cj;
      float cnew = CA * wx1 + CB * gl[jj] * cadj;
      vv = tanh_fast(cnew);
      ovv = gl[256 + jj] * vv;
      cv_keep = cnew; ov_keep = ovv;
      HpubB[(q << 7) + jj] = f16b(ovv);
      CpubB[(q << 7) + jj] = cnew;
    }
    {
      float sv = wred(vv * vv), so = wred(ovv * ovv);
      if (!isG && lane == 0) { pw[wv - 8][0] = sv; pw[wv - 8][1] = so; }
    }
    __syncthreads();
    if (t == 0) {
      float* pd = PD + ((b << 2) + q) * 4;
      pd[0] = pw[0][0] + pw[1][0];
      pd[1] = pw[0][1] + pw[1][1];
    }
    __threadfence();
    __syncthreads();
    if (t == 0) atomicAdd(F1, 1u);
  }

  // ===== final: resolve deferred HS for h_final ============================
  if (t == 0) {
    while (poll_flag(F1) < 4u * 129u)
      __builtin_amdgcn_s_sleep(1);
  }
  __syncthreads();
  __threadfence();
  {
    float Ssv = 0.f, Sso = 0.f;
    #pragma unroll
    for (int qq = 0; qq < 4; ++qq) {
      const float* pd = PD + ((b << 2) + qq) * 4;
      Ssv += pd[0]; Sso += pd[1];
    }
    float vn = fmaxf(sqrtf(Ssv), MINN);
    float te = tanh_fast(vn);
    float ke = te / vn;
    float xnh = fmaxf(te, MINN);
    float wxnh = fmaxf(ke * sqrtf(Sso), MINN);
    float th = tanh_fast((wxnh / xnh) * artanh_c(xnh));
    float HSf = (th / wxnh) * ke;
    if (!isG) {
      int jj = t - 512;
      OutH[b * 512 + (q << 7) + jj] = HSf * ov_keep;
      OutC[b * 512 + (q << 7) + jj] = cv_keep;
    }
  }
}

extern "C" void kernel_launch(void* const* d_in, const int* in_sizes, int n_in,
                              void* d_out, int out_size, void* d_ws, size_t ws_size,
                              hipStream_t stream) {
  const float* inputs = (const float*)d_in[0];   // [64,128,512]
  const float* tsg    = (const float*)d_in[1];   // [64,128]
  const float* h0g    = (const float*)d_in[2];   // [64,512]
  const float* c0g    = (const float*)d_in[3];   // [64,512]
  const float* Wall   = (const float*)d_in[4];   // [512,2048]
  const float* Uall   = (const float*)d_in[5];   // [2048,512]
  const float* Wd     = (const float*)d_in[6];   // [512,512]
  char* ws = (char*)d_ws;

  uint4* W3   = (uint4*)(ws + 0);                // 2 MB
  uint4* WD3  = (uint4*)(ws + 2097152);          // 512 KB
  u16*   XB   = (u16*)(ws + 2621440);            // 8 MB
  u16*   UB   = (u16*)(ws + 11010048);           // 2 MB
  u16*   MXU  = (u16*)(ws + 13107200);           // 32 MB
  float* XN2  = (float*)(ws + 46661632);         // 32 KB
  float* SU   = (float*)(ws + 46694400);         // 128 KB
  float* UY2  = (float*)(ws + 46825472);         // 128 KB
  u16*   Hpub = (u16*)(ws + 46956544);           // 64 KB
  float* Cpub = (float*)(ws + 47022080);         // 128 KB
  float* PA   = (float*)(ws + 47153152);         // 16 KB
  float* PB   = (float*)(ws + 47169536);         // 16 KB
  float* PD   = (float*)(ws + 47185920);         // 4 KB
  u32*   FLG  = (u32*)(ws + 47190016);           // 12 KB

  float* out = (float*)d_out;
  float* out_o = out;                            // [64,128,512]
  float* out_h = out + 4194304;                  // [64,512]
  float* out_c = out + 4227072;                  // [64,512]

  k_pack2<<<653, 256, 0, stream>>>(Wall, Wd, W3, WD3, FLG);
  k_convert_x<<<8192, 256, 0, stream>>>(inputs, XB, XN2);
  k_convert_u<<<4096, 256, 0, stream>>>(Uall, UB);
  k_gemm<<<dim3(16, 64), 256, 0, stream>>>(XB, UB, MXU);
  k_scale<<<8192, 256, 0, stream>>>(MXU, XN2, SU, UY2);
  k_scan2<<<256, 640, 0, stream>>>(W3, WD3, MXU, SU, UY2, tsg, h0g, c0g,
                                   Hpub, Cpub, PA, PB, PD, FLG,
                                   out_o, out_h, out_c);
}

// Round 9
// 4051.122 us; speedup vs baseline: 7.7990x; 7.7774x over previous
//
#include <hip/hip_runtime.h>
#include <hip/hip_fp16.h>

typedef unsigned int u32;
typedef unsigned short u16;
typedef _Float16 h2v __attribute__((ext_vector_type(2)));
typedef short short8 __attribute__((ext_vector_type(8)));
typedef float f32x4 __attribute__((ext_vector_type(4)));

#define MINN 1e-15f

// Poll: RELAXED RMW (coherent point, always fresh — R7).
__device__ __forceinline__ u32 poll_flag(u32* f){
  return __hip_atomic_fetch_add(f, 0u, __ATOMIC_RELAXED, __HIP_MEMORY_SCOPE_AGENT);
}
// Signal: RELEASE RMW executed by ONE thread. Prior __syncthreads guarantees all
// waves' stores reached L2 (compiler drains vmcnt before s_barrier); the release
// does ONE buffer_wbl2 to push them to the coherence point.
// R5/R7 lesson: ALL-THREAD __threadfence() (10 waves x ~6/step x buffer_wbl2+inv)
// serialized at the XCD L2 -> ~73us/round. Fence work must be t0-only.
__device__ __forceinline__ void signal_release(u32* f){
  __hip_atomic_fetch_add(f, 1u, __ATOMIC_RELEASE, __HIP_MEMORY_SCOPE_AGENT);
}

__device__ __forceinline__ float wred(float v){
  #pragma unroll
  for (int m = 32; m > 0; m >>= 1) v += __shfl_xor(v, m, 64);
  return v;
}
__device__ __forceinline__ float bf2f(u32 lo16){ u32 u = lo16 << 16; return __builtin_bit_cast(float, u); }
__device__ __forceinline__ u16 f2bf(float f){
  u32 u = __builtin_bit_cast(u32, f);
  u32 r = (u + 0x7fffu + ((u >> 16) & 1u)) >> 16;
  return (u16)r;
}
__device__ __forceinline__ u16 f16b(float x){ __half h = __float2half(x); return __builtin_bit_cast(u16, h); }
__device__ __forceinline__ u32 pkh(float a, float b){
  u32 lo = f16b(a), hi = f16b(b);
  return lo | (hi << 16);
}
__device__ __forceinline__ float fdot2_(u32 a, u32 b, float c){
  return __builtin_amdgcn_fdot2(__builtin_bit_cast(h2v, a), __builtin_bit_cast(h2v, b), c, false);
}
__device__ __forceinline__ float tanh_fast(float x){
  float e = __expf(-2.f * fabsf(x));
  float t = (1.f - e) / (1.f + e);
  return x < 0.f ? -t : t;
}
__device__ __forceinline__ float artanh_c(float x){
  x = fminf(fmaxf(x, -1.f + 1e-5f), 1.f - 1e-5f);
  return 0.5f * __logf((1.f + x) / (1.f - x));
}
__device__ __forceinline__ float sigm(float x){ return 1.f / (1.f + __expf(-x)); }

// ---------------- weight repack for split scan -----------------------------
__global__ void k_pack2(const float* __restrict__ Wall, const float* __restrict__ Wd,
                        uint4* __restrict__ W3, uint4* __restrict__ WD3, u32* __restrict__ flags){
  int i = blockIdx.x * 256 + threadIdx.x;
  if (i < 131072) {
    int q = i >> 15, rem = i & 32767, kk = rem >> 9, col = rem & 511;
    int g = col >> 7, ii = (q << 7) + (col & 127);
    const float* bsrc = Wall + (size_t)ii * 2048 + (g << 9) + (kk << 3);
    uint4 o;
    o.x = pkh(bsrc[0], bsrc[1]); o.y = pkh(bsrc[2], bsrc[3]);
    o.z = pkh(bsrc[4], bsrc[5]); o.w = pkh(bsrc[6], bsrc[7]);
    W3[i] = o;
  } else if (i < 163840) {
    int e = i - 131072;
    int q = e >> 13, rem = e & 8191, kk = rem >> 7, j = rem & 127;
    int j0 = (q << 7) + j;
    const float* bsrc = Wd + (size_t)j0 * 512 + (kk << 3);
    uint4 o;
    o.x = pkh(bsrc[0], bsrc[1]); o.y = pkh(bsrc[2], bsrc[3]);
    o.z = pkh(bsrc[4], bsrc[5]); o.w = pkh(bsrc[6], bsrc[7]);
    WD3[e] = o;
  } else if (i < 163840 + 3072) {
    flags[i - 163840] = 0u;
  }
}

// ---------------- x -> bf16 + per-row |x|^2 --------------------------------
__global__ void k_convert_x(const float* __restrict__ X, u16* __restrict__ Xb, float* __restrict__ xn2){
  int r = blockIdx.x, t = threadIdx.x;
  const float* row = X + (size_t)r * 512;
  float v0 = row[t], v1 = row[t + 256];
  Xb[(size_t)r * 512 + t] = f2bf(v0);
  Xb[(size_t)r * 512 + t + 256] = f2bf(v1);
  float s = wred(v0 * v0 + v1 * v1);
  __shared__ float p[4];
  if ((t & 63) == 0) p[t >> 6] = s;
  __syncthreads();
  if (t == 0) xn2[r] = p[0] + p[1] + p[2] + p[3];
}

__global__ void k_convert_u(const float* __restrict__ U, u16* __restrict__ Ub){
  int i = blockIdx.x * 256 + threadIdx.x;
  Ub[i] = f2bf(U[i]);
}

// ---------------- mxU = X @ U^T, bf16 MFMA ---------------------------------
__global__ void __launch_bounds__(256) k_gemm(const u16* __restrict__ A, const u16* __restrict__ B,
                                              u16* __restrict__ C){
  __shared__ u16 Al[128 * 32];
  __shared__ u16 Bl[128 * 32];
  int t = threadIdx.x;
  int bn = blockIdx.x, bm = blockIdx.y;
  int w = t >> 6, l = t & 63;
  int wr = w >> 1, wc = w & 1;
  f32x4 zero = {0.f, 0.f, 0.f, 0.f};
  f32x4 acc[4][4];
  #pragma unroll
  for (int m = 0; m < 4; ++m)
    #pragma unroll
    for (int n = 0; n < 4; ++n) acc[m][n] = zero;

  for (int kt = 0; kt < 16; ++kt) {
    #pragma unroll
    for (int i = 0; i < 2; ++i) {
      int off = t + i * 256;
      int r = off >> 2, ch = off & 3;
      *(uint4*)&Al[(size_t)off * 8] = *(const uint4*)(A + (size_t)(bm * 128 + r) * 512 + kt * 32 + ch * 8);
      *(uint4*)&Bl[(size_t)off * 8] = *(const uint4*)(B + (size_t)(bn * 128 + r) * 512 + kt * 32 + ch * 8);
    }
    __syncthreads();
    int ko = (l >> 4) * 8;
    short8 af[4], bfr[4];
    #pragma unroll
    for (int m = 0; m < 4; ++m) af[m] = *(const short8*)&Al[(wr * 64 + m * 16 + (l & 15)) * 32 + ko];
    #pragma unroll
    for (int n = 0; n < 4; ++n) bfr[n] = *(const short8*)&Bl[(wc * 64 + n * 16 + (l & 15)) * 32 + ko];
    #pragma unroll
    for (int m = 0; m < 4; ++m)
      #pragma unroll
      for (int n = 0; n < 4; ++n)
        acc[m][n] = __builtin_amdgcn_mfma_f32_16x16x32_bf16(af[m], bfr[n], acc[m][n], 0, 0, 0);
    __syncthreads();
  }
  int cr = (l >> 4) * 4, cc = l & 15;
  #pragma unroll
  for (int m = 0; m < 4; ++m)
    #pragma unroll
    for (int n = 0; n < 4; ++n)
      #pragma unroll
      for (int r2 = 0; r2 < 4; ++r2) {
        int row = bm * 128 + wr * 64 + m * 16 + cr + r2;
        int col = bn * 128 + wc * 64 + n * 16 + cc;
        C[(size_t)row * 2048 + col] = f2bf(acc[m][n][r2]);
      }
}

// ---------------- per-(row,gate) U-path scalars ----------------------------
__global__ void k_scale(const u16* __restrict__ MXU, const float* __restrict__ xn2,
                        float* __restrict__ SU, float* __restrict__ UY2){
  int r = blockIdx.x, t = threadIdx.x;
  const u16* row = MXU + (size_t)r * 2048;
  uint4 q = *(const uint4*)(row + t * 8);
  float s = 0.f;
  s += bf2f(q.x & 0xffffu) * bf2f(q.x & 0xffffu) + bf2f(q.x >> 16) * bf2f(q.x >> 16);
  s += bf2f(q.y & 0xffffu) * bf2f(q.y & 0xffffu) + bf2f(q.y >> 16) * bf2f(q.y >> 16);
  s += bf2f(q.z & 0xffffu) * bf2f(q.z & 0xffffu) + bf2f(q.z >> 16) * bf2f(q.z >> 16);
  s += bf2f(q.w & 0xffffu) * bf2f(q.w & 0xffffu) + bf2f(q.w >> 16) * bf2f(q.w >> 16);
  s = wred(s);
  if ((t & 63) == 0) {
    int g = t >> 6;
    float mxn = fmaxf(sqrtf(s), MINN);
    float xn = fmaxf(sqrtf(xn2[r]), MINN);
    float tb = tanh_fast((mxn / xn) * artanh_c(xn));
    SU[r * 4 + g] = tb / mxn;
    UY2[r * 4 + g] = tb * tb;
  }
}

// ---------------- split persistent scan ------------------------------------
// 256 blocks x 640 threads. bid: q = bid>>6 (column slice), b = bid&63.
// Per step: 3 flag rounds; ALL fence/cache-maintenance work is t0-only.
// PA/PB/PD padded to 128B per (b,q): no cross-writer cache-line sharing.
__global__ void __launch_bounds__(640) k_scan2(
    const uint4* __restrict__ W3, const uint4* __restrict__ WD3,
    const u16* __restrict__ MXU, const float* __restrict__ SU, const float* __restrict__ UY2,
    const float* __restrict__ TS, const float* __restrict__ H0, const float* __restrict__ C0,
    u16* __restrict__ Hpub, float* __restrict__ Cpub,
    float* __restrict__ PA, float* __restrict__ PB, float* __restrict__ PD,
    u32* __restrict__ flags,
    float* __restrict__ OutO, float* __restrict__ OutH, float* __restrict__ OutC)
{
  const int bid = blockIdx.x, t = threadIdx.x;
  const int q = bid >> 6, b = bid & 63;
  const int lane = t & 63, wv = t >> 6;
  const bool isG = (t < 512);
  const int g = t >> 7;            // gate (valid when isG)
  const int j = t & 127;           // local index within slice

  u32* F1 = flags + b * 48;
  u32* F2 = F1 + 16;
  u32* F3 = F1 + 32;

  __shared__ __align__(16) u16 Hl[512];
  __shared__ __align__(16) u16 Chl[512];
  __shared__ float Cl[512];
  __shared__ float gl[512];
  __shared__ float ul[128];
  __shared__ float pw[10][2];

  const u32* Hl32 = (const u32*)Hl;
  u16* HpubB = Hpub + b * 512;
  float* CpubB = Cpub + b * 512;

  // ---- init publication (counts as F1 publication #1)
  float hv0 = 0.f, cv0 = 0.f;
  if (!isG) {
    int gi = b * 512 + (q << 7) + (t - 512);
    hv0 = H0[gi]; cv0 = C0[gi];
    HpubB[(q << 7) + (t - 512)] = f16b(hv0);
    CpubB[(q << 7) + (t - 512)] = cv0;
  }
  {
    float sh = wred(hv0 * hv0), sc = wred(cv0 * cv0);
    if (!isG && lane == 0) { pw[wv - 8][0] = sh; pw[wv - 8][1] = sc; }
  }
  __syncthreads();
  if (t == 0) {
    float s0 = pw[0][0] + pw[1][0], s1 = pw[0][1] + pw[1][1];
    float* pd = PD + ((b << 2) + q) * 32;
    pd[0] = s0; pd[1] = s0; pd[2] = s1;
    signal_release(F1);
  }

  const size_t outOb = (size_t)b * (128 * 512);
  float cn2 = 0.f;                 // carried; set at s=0 from PD[2]
  float ov_keep = 0.f, cv_keep = 0.f;

  for (int s = 0; s < 128; ++s) {
    const int row = b * 128 + s;
    const u32 tgt = 4u * (u32)(s + 1);

    // ===== round A: wait for h/c/deferred publication ======================
    if (t == 0) {
      while (poll_flag(F1) < tgt)
        __builtin_amdgcn_s_sleep(1);
      __threadfence();             // ONE acquire (inv) for the whole block/CU
    }
    __syncthreads();

    float ux = 0.f;                // issue MXU row load early (independent)
    if (isG) ux = bf2f((u32)MXU[(size_t)row * 2048 + (g << 9) + (q << 7) + j]);

    if (isG) {
      Hl[t] = HpubB[t];
      float cc = CpubB[t];
      Cl[t] = cc; Chl[t] = f16b(cc);
    }
    // deferred h-scalars
    float Ssv = 0.f, Sso = 0.f, Sc0 = 0.f;
    #pragma unroll
    for (int qq = 0; qq < 4; ++qq) {
      const float* pd = PD + ((b << 2) + qq) * 32;
      Ssv += pd[0]; Sso += pd[1]; Sc0 += pd[2];
    }
    float HS, hn;
    if (s == 0) {
      HS = 1.f;
      hn = fmaxf(sqrtf(Sso), MINN);
      cn2 = Sc0;
    } else {
      float vn = fmaxf(sqrtf(Ssv), MINN);
      float te = tanh_fast(vn);
      float ke = te / vn;
      float xnh = fmaxf(te, MINN);
      float wxnh = fmaxf(ke * sqrtf(Sso), MINN);
      float th = tanh_fast((wxnh / xnh) * artanh_c(xnh));
      HS = (th / wxnh) * ke;
      hn = fmaxf(th, MINN);
    }
    float cn = fmaxf(sqrtf(cn2), MINN);
    const float tsv = TS[b * 128 + s];
    __syncthreads();               // LDS h/c ready

    // ===== matvec ==========================================================
    float av = 0.f;
    if (isG) {
      const uint4* Wp = W3 + (q << 15) + t;
      #pragma unroll 4
      for (int kk = 0; kk < 64; ++kk) {
        uint4 wq = Wp[kk << 9];
        uint4 hp = *(const uint4*)&Hl32[kk << 2];
        av = fdot2_(wq.x, hp.x, av); av = fdot2_(wq.y, hp.y, av);
        av = fdot2_(wq.z, hp.z, av); av = fdot2_(wq.w, hp.w, av);
      }
      av *= HS;
    } else {
      const uint4* Wp = WD3 + (q << 13) + (t - 512);
      const u32* Cl32 = (const u32*)Chl;
      #pragma unroll 4
      for (int kk = 0; kk < 64; ++kk) {
        uint4 wq = Wp[kk << 7];
        uint4 cp = *(const uint4*)&Cl32[kk << 2];
        av = fdot2_(wq.x, cp.x, av); av = fdot2_(wq.y, cp.y, av);
        av = fdot2_(wq.z, cp.z, av); av = fdot2_(wq.w, cp.w, av);
      }
    }

    {
      float s0 = wred(av * av);
      float s1 = wred(isG ? av * ux : 0.f);
      if (lane == 0) { pw[wv][0] = s0; pw[wv][1] = s1; }
    }
    __syncthreads();
    if (t < 9) {
      float val;
      if (t < 8) { int gg = t >> 1, e = t & 1; val = pw[2 * gg][e] + pw[2 * gg + 1][e]; }
      else       { val = pw[8][0] + pw[9][0]; }
      PA[((b << 2) + q) * 32 + t] = val;
    }
    __syncthreads();               // PA stores drained (vmcnt0 before s_barrier)
    if (t == 0) {
      signal_release(F2);          // ONE wbl2 + signal
      while (poll_flag(F2) < tgt)
        __builtin_amdgcn_s_sleep(1);
      __threadfence();             // ONE inv
    }
    __syncthreads();

    // ===== round A scalars + elementwise gates / u =========================
    float uval = 0.f;
    if (isG) {
      float gsq = 0.f, gdt = 0.f;
      #pragma unroll
      for (int qq = 0; qq < 4; ++qq) {
        const float* pa = PA + ((b << 2) + qq) * 32;
        gsq += pa[2 * g]; gdt += pa[2 * g + 1];
      }
      float su_ = SU[row * 4 + g], y2 = UY2[row * 4 + g];
      float mxn = fmaxf(sqrtf(gsq), MINN);
      float tw = tanh_fast((mxn / hn) * artanh_c(hn));
      float x2 = tw * tw;
      float sw = tw / mxn;
      float xy = sw * su_ * gdt;
      float na = 1.f + 2.f * xy + y2, nb = 1.f - x2;
      float den = fmaxf(1.f + 2.f * xy + x2 * y2, MINN);
      float addn2 = fmaxf((na * na * x2 + 2.f * na * nb * xy + nb * nb * y2) / (den * den), 0.f);
      float an = fmaxf(sqrtf(addn2), MINN);
      float lam = artanh_c(an) / an;
      float GA = lam * na * sw / den, GB = lam * nb * su_ / den;
      float gval = sigm(GA * av + GB * ux);
      gl[t] = gval;
      if (g == 2) OutO[outOb + (size_t)s * 512 + (q << 7) + j] = gval;
    } else {
      float md2 = 0.f;
      #pragma unroll
      for (int qq = 0; qq < 4; ++qq) md2 += PA[((b << 2) + qq) * 32 + 8];
      float mdn = fmaxf(sqrtf(md2), MINN);
      float alc = tanh_fast((mdn / cn) * artanh_c(cn));
      float ycl = fmaxf(alc, MINN);
      float DS = (artanh_c(ycl) / ycl) * alc / mdn;
      uval = tanh_fast(DS * av);
      ul[t - 512] = uval;
    }
    __syncthreads();

    // ===== bilinear partial sums (9 sums over local j in [0,128)) ==========
    if (wv < 9) {
      float acc2 = 0.f;
      #pragma unroll
      for (int rep = 0; rep < 2; ++rep) {
        int jj = lane + rep * 64;
        float fj = gl[jj], ij = gl[128 + jj], cgj = gl[384 + jj];
        float uj = ul[jj], cj = Cl[(q << 7) + jj];
        float wx1 = ij * cgj;
        float p;
        if      (wv == 0) p = uj * uj;
        else if (wv == 1) p = uj * cj;
        else if (wv == 2) p = cgj * cgj;
        else if (wv == 3) p = wx1 * wx1;
        else if (wv == 4) p = fj * fj * uj * uj;
        else if (wv == 5) p = fj * fj * uj * cj;
        else if (wv == 6) p = fj * fj * cj * cj;
        else if (wv == 7) p = wx1 * fj * uj;
        else              p = wx1 * fj * cj;
        acc2 += p;
      }
      acc2 = wred(acc2);
      if (lane == 0) PB[((b << 2) + q) * 32 + wv] = acc2;
    }
    __syncthreads();               // PB stores drained
    if (t == 0) {
      signal_release(F3);
      while (poll_flag(F3) < tgt)
        __builtin_amdgcn_s_sleep(1);
      __threadfence();
    }
    __syncthreads();

    // ===== combine bilinear sums, scalar chain (all threads, redundant) ====
    float S0 = 0.f, S1 = 0.f, S2 = 0.f, S3 = 0.f, S4 = 0.f, S5 = 0.f, S6 = 0.f, S7 = 0.f, S8 = 0.f;
    #pragma unroll
    for (int qq = 0; qq < 4; ++qq) {
      const float* pb = PB + ((b << 2) + qq) * 32;
      S0 += pb[0]; S1 += pb[1]; S2 += pb[2]; S3 += pb[3]; S4 += pb[4];
      S5 += pb[5]; S6 += pb[6]; S7 += pb[7]; S8 += pb[8];
    }
    float usq = S0, duc = S1;
    float un = fmaxf(sqrtf(usq), MINN);
    float t1 = tanh_fast(un);
    float at1 = artanh_c(t1);
    float k1 = t1 / un;
    float k2 = tanh_fast(tsv * at1) / un;
    float x2l = t1 * t1;
    float xyl = -k1 * duc;
    float nal = 1.f + 2.f * xyl + cn2;
    float nbl = 1.f - x2l;
    float denl = fmaxf(1.f + 2.f * xyl + x2l * cn2, MINN);
    float p1 = -nal * k1 / denl, p2 = nbl / denl;
    float cl2 = fmaxf(p1 * p1 * usq + 2.f * p1 * p2 * duc + p2 * p2 * cn2, 0.f);
    float cs2n2 = k2 * k2 * usq;
    float xya = k2 * (p1 * usq + p2 * duc);
    float naa = 1.f + 2.f * xya + cs2n2;
    float nba = 1.f - cl2;
    float dena = fmaxf(1.f + 2.f * xya + cl2 * cs2n2, MINN);
    float r1 = (naa * p1 + nba * k2) / dena;
    float r2 = naa * p2 / dena;
    float cadj2 = fmaxf(r1 * r1 * usq + 2.f * r1 * r2 * duc + r2 * r2 * cn2, 0.f);

    float xnp = fmaxf(sqrtf(S2), MINN);
    float wxnp = fmaxf(sqrtf(S3), MINN);
    float tp = tanh_fast((wxnp / xnp) * artanh_c(xnp));
    float s1c = tp / wxnp;
    float Ssw2 = r1 * r1 * S4 + 2.f * r1 * r2 * S5 + r2 * r2 * S6;
    float xnq = fmaxf(sqrtf(cadj2), MINN);
    float wxnq = fmaxf(sqrtf(Ssw2), MINN);
    float tq = tanh_fast((wxnq / xnq) * artanh_c(xnq));
    float s2c = tq / wxnq;
    float Ss12 = r1 * S7 + r2 * S8;
    float xyn = s1c * s2c * Ss12;
    float na2 = 1.f + 2.f * xyn + tq * tq;
    float nb2 = 1.f - tp * tp;
    float den2 = fmaxf(1.f + 2.f * xyn + tp * tp * tq * tq, MINN);
    float CA = na2 * s1c / den2, CB = nb2 * s2c / den2;
    cn2 = fmaxf((na2 * na2 * tp * tp + 2.f * na2 * nb2 * xyn + nb2 * nb2 * tq * tq) / (den2 * den2), 0.f);

    // ===== elementwise c_new / v / ov + publish ============================
    float vv = 0.f, ovv = 0.f;
    if (!isG) {
      int jj = t - 512;
      float cj = Cl[(q << 7) + jj];
      float wx1 = gl[128 + jj] * gl[384 + jj];
      float cadj = r1 * uval + r2 * cj;
      float cnew = CA * wx1 + CB * gl[jj] * cadj;
      vv = tanh_fast(cnew);
      ovv = gl[256 + jj] * vv;
      cv_keep = cnew; ov_keep = ovv;
      HpubB[(q << 7) + jj] = f16b(ovv);
      CpubB[(q << 7) + jj] = cnew;
    }
    {
      float sv = wred(vv * vv), so = wred(ovv * ovv);
      if (!isG && lane == 0) { pw[wv - 8][0] = sv; pw[wv - 8][1] = so; }
    }
    __syncthreads();               // Hpub/Cpub + pw drained
    if (t == 0) {
      float* pd = PD + ((b << 2) + q) * 32;
      pd[0] = pw[0][0] + pw[1][0];
      pd[1] = pw[0][1] + pw[1][1];
      signal_release(F1);          // release covers t0's pd stores + peers' via barrier
    }
  }

  // ===== final: resolve deferred HS for h_final ============================
  if (t == 0) {
    while (poll_flag(F1) < 4u * 129u)
      __builtin_amdgcn_s_sleep(1);
    __threadfence();
  }
  __syncthreads();
  {
    float Ssv = 0.f, Sso = 0.f;
    #pragma unroll
    for (int qq = 0; qq < 4; ++qq) {
      const float* pd = PD + ((b << 2) + qq) * 32;
      Ssv += pd[0]; Sso += pd[1];
    }
    float vn = fmaxf(sqrtf(Ssv), MINN);
    float te = tanh_fast(vn);
    float ke = te / vn;
    float xnh = fmaxf(te, MINN);
    float wxnh = fmaxf(ke * sqrtf(Sso), MINN);
    float th = tanh_fast((wxnh / xnh) * artanh_c(xnh));
    float HSf = (th / wxnh) * ke;
    if (!isG) {
      int jj = t - 512;
      OutH[b * 512 + (q << 7) + jj] = HSf * ov_keep;
      OutC[b * 512 + (q << 7) + jj] = cv_keep;
    }
  }
}

extern "C" void kernel_launch(void* const* d_in, const int* in_sizes, int n_in,
                              void* d_out, int out_size, void* d_ws, size_t ws_size,
                              hipStream_t stream) {
  const float* inputs = (const float*)d_in[0];   // [64,128,512]
  const float* tsg    = (const float*)d_in[1];   // [64,128]
  const float* h0g    = (const float*)d_in[2];   // [64,512]
  const float* c0g    = (const float*)d_in[3];   // [64,512]
  const float* Wall   = (const float*)d_in[4];   // [512,2048]
  const float* Uall   = (const float*)d_in[5];   // [2048,512]
  const float* Wd     = (const float*)d_in[6];   // [512,512]
  char* ws = (char*)d_ws;

  uint4* W3   = (uint4*)(ws + 0);                // 2 MB
  uint4* WD3  = (uint4*)(ws + 2097152);          // 512 KB
  u16*   XB   = (u16*)(ws + 2621440);            // 8 MB
  u16*   UB   = (u16*)(ws + 11010048);           // 2 MB
  u16*   MXU  = (u16*)(ws + 13107200);           // 32 MB
  float* XN2  = (float*)(ws + 46661632);         // 32 KB
  float* SU   = (float*)(ws + 46694400);         // 128 KB
  float* UY2  = (float*)(ws + 46825472);         // 128 KB
  u16*   Hpub = (u16*)(ws + 46956544);           // 64 KB
  float* Cpub = (float*)(ws + 47022080);         // 128 KB
  float* PA   = (float*)(ws + 47153152);         // 32 KB (128B per (b,q))
  float* PB   = (float*)(ws + 47185920);         // 32 KB
  float* PD   = (float*)(ws + 47218688);         // 32 KB
  u32*   FLG  = (u32*)(ws + 47251456);           // 12 KB

  float* out = (float*)d_out;
  float* out_o = out;                            // [64,128,512]
  float* out_h = out + 4194304;                  // [64,512]
  float* out_c = out + 4227072;                  // [64,512]

  k_pack2<<<653, 256, 0, stream>>>(Wall, Wd, W3, WD3, FLG);
  k_convert_x<<<8192, 256, 0, stream>>>(inputs, XB, XN2);
  k_convert_u<<<4096, 256, 0, stream>>>(Uall, UB);
  k_gemm<<<dim3(16, 64), 256, 0, stream>>>(XB, UB, MXU);
  k_scale<<<8192, 256, 0, stream>>>(MXU, XN2, SU, UY2);
  k_scan2<<<256, 640, 0, stream>>>(W3, WD3, MXU, SU, UY2, tsg, h0g, c0g,
                                   Hpub, Cpub, PA, PB, PD, FLG,
                                   out_o, out_h, out_c);
}